// Round 5
// baseline (235.219 us; speedup 1.0000x reference)
//
#include <hip/hip_runtime.h>

#define ROWLEN 4096
#define TPB    256
#define LOG2E  1.44269504088896340736f

typedef float f32x4 __attribute__((ext_vector_type(4)));

__device__ __forceinline__ float exp2_fast(float x) {
    float r; asm("v_exp_f32 %0, %1" : "=v"(r) : "v"(x)); return r;
}
__device__ __forceinline__ float rcp_fast(float x) {
    float r; asm("v_rcp_f32 %0, %1" : "=v"(r) : "v"(x)); return r;
}
__device__ __forceinline__ float log2_fast(float x) {
    float r; asm("v_log_f32 %0, %1" : "=v"(r) : "v"(x)); return r;
}
__device__ __forceinline__ float sqrt_fast(float x) {
    float r; asm("v_sqrt_f32 %0, %1" : "=v"(r) : "v"(x)); return r;
}

// sigmoid(z) = 1/(1+e^-z) = 1/(1+2^(-z*log2e)); caller passes tnu = -LOG2E*nu
__device__ __forceinline__ float sig_from(float v, float tnu) {
    float e = exp2_fast(fmaf(v, -LOG2E, tnu));
    return rcp_fast(1.0f + e);
}

// One wave (64 lanes) per row; 64 elements per lane held in VGPRs.
// No __syncthreads, no LDS: all reductions are 6-step __shfl_xor chains,
// result already broadcast to every lane.
__global__ __launch_bounds__(TPB) void lml_kernel(const float* __restrict__ x,
                                                  float* __restrict__ out) {
    const int lane = threadIdx.x & 63;
    const size_t row = (size_t)blockIdx.x * 4 + (threadIdx.x >> 6);
    const f32x4* __restrict__ rp = reinterpret_cast<const f32x4*>(x + row * ROWLEN);
    f32x4* __restrict__ op = reinterpret_cast<f32x4*>(out + row * ROWLEN);

    // ---- sweep A: load row (coalesced float4), accumulate S1=sum e^x, S2=sum e^2x ----
    float v[64];
#pragma unroll
    for (int k = 0; k < 16; ++k) {
        f32x4 f = rp[k * 64 + lane];
        v[4*k+0] = f.x; v[4*k+1] = f.y; v[4*k+2] = f.z; v[4*k+3] = f.w;
    }

    float s10 = 0, s11 = 0, s12 = 0, s13 = 0;
    float s20 = 0, s21 = 0, s22 = 0, s23 = 0;
#pragma unroll
    for (int k = 0; k < 16; ++k) {
        float e0 = exp2_fast(v[4*k+0] * LOG2E);
        float e1 = exp2_fast(v[4*k+1] * LOG2E);
        float e2 = exp2_fast(v[4*k+2] * LOG2E);
        float e3 = exp2_fast(v[4*k+3] * LOG2E);
        s10 += e0; s11 += e1; s12 += e2; s13 += e3;
        s20 = fmaf(e0, e0, s20); s21 = fmaf(e1, e1, s21);
        s22 = fmaf(e2, e2, s22); s23 = fmaf(e3, e3, s23);
    }
    float S1 = (s10 + s11) + (s12 + s13);
    float S2 = (s20 + s21) + (s22 + s23);
#pragma unroll
    for (int off = 32; off >= 1; off >>= 1) {
        S1 += __shfl_xor(S1, off, 64);
        S2 += __shfl_xor(S2, off, 64);
    }

    // ---- analytic two-sided bracket ----
    // sigma(z) <= e^z           => nu_L = ln(64/S1) has f(nu_L) <= 64  (lower bracket)
    // sigma(z) >= e^z - e^{2z}  => quadratic root nu_Q has f(nu_Q) >= 64 (upper bracket)
    //   S1*t - S2*t^2 = 64  =>  t = 128 / (S1 + sqrt(S1^2 - 256*S2))   (clamped disc)
    float disc = fmaxf(fmaf(S1, S1, -256.0f * S2), 0.0f);
    float lo = (6.0f - log2_fast(S1)) * (1.0f / LOG2E);
    float hi = (7.0f - log2_fast(S1 + sqrt_fast(disc))) * (1.0f / LOG2E);
    float nu = 0.5f * (lo + hi);

    // ---- 2 safeguarded log-space Newton sweeps ----
#pragma unroll 1
    for (int it = 0; it < 2; ++it) {
        const float tnu = -LOG2E * nu;
        float a0 = 0, a1 = 0, a2 = 0, a3 = 0;
        float b0 = 0, b1 = 0, b2 = 0, b3 = 0;
#pragma unroll
        for (int k = 0; k < 16; ++k) {
            float x0 = sig_from(v[4*k+0], tnu);
            float x1 = sig_from(v[4*k+1], tnu);
            float x2 = sig_from(v[4*k+2], tnu);
            float x3 = sig_from(v[4*k+3], tnu);
            a0 += x0; a1 += x1; a2 += x2; a3 += x3;
            b0 = fmaf(x0, -x0, b0 + x0); b1 = fmaf(x1, -x1, b1 + x1);
            b2 = fmaf(x2, -x2, b2 + x2); b3 = fmaf(x3, -x3, b3 + x3);
        }
        float fs = (a0 + a1) + (a2 + a3);
        float fw = (b0 + b1) + (b2 + b3);
#pragma unroll
        for (int off = 32; off >= 1; off >>= 1) {
            fs += __shfl_xor(fs, off, 64);
            fw += __shfl_xor(fw, off, 64);
        }
        if (fs < 64.0f) lo = nu; else hi = nu;   // keep valid bracket
        const float h = (log2_fast(fs) - 6.0f) * (1.0f / LOG2E);  // ln(fs/64)
        float nun = nu - h * fs * rcp_fast(fmaxf(fw, 1e-20f));
        if (!(nun > lo && nun < hi)) nun = 0.5f * (lo + hi);      // safeguard
        nu = nun;
    }

    // ---- final output sweep (coalesced nontemporal float4 store) ----
    const float tnu = -LOG2E * nu;
#pragma unroll
    for (int k = 0; k < 16; ++k) {
        f32x4 f;
        f.x = sig_from(v[4*k+0], tnu);
        f.y = sig_from(v[4*k+1], tnu);
        f.z = sig_from(v[4*k+2], tnu);
        f.w = sig_from(v[4*k+3], tnu);
        __builtin_nontemporal_store(f, op + k * 64 + lane);
    }
}

extern "C" void kernel_launch(void* const* d_in, const int* in_sizes, int n_in,
                              void* d_out, int out_size, void* d_ws, size_t ws_size,
                              hipStream_t stream) {
    const float* x = (const float*)d_in[0];
    float* out = (float*)d_out;
    const int rows = in_sizes[0] / ROWLEN;        // 8192
    lml_kernel<<<rows / 4, TPB, 0, stream>>>(x, out);
}